// Round 1
// baseline (756.791 us; speedup 1.0000x reference)
//
#include <hip/hip_runtime.h>
#include <hip/hip_bf16.h>

// GlobalAggregator: B=256, N=256, K=16, DIM=128
//   gated = extra[:,:,None,:] * neighbor                  [B,N,K,128]
//   alpha = gated @ w1[:128] + weight[...,None]*w1[128]   [B,N,K,128]
//   alpha = leaky_relu(alpha, 0.2) @ w2                   [B,N,K]
//   alpha = softmax(alpha, axis=K)
//   out   = sum_k alpha * neighbor                        [B,N,128]
//
// Strategy: bf16 MFMA (16x16x32) for the 34 GFLOP matmul (fp32 VALU would be
// 219us compute-bound; bf16 MFMA is 17us -> HBM-bound ~100us). Everything
// else fp32. One wave per (b,n) position; M=16 rows = K neighbors exactly.

#define KN 16
#define DIM 128
#define POS_PER_WAVE 8
#define WAVES_PER_BLOCK 4

typedef __bf16 bf16_t;
typedef bf16_t bf16x8 __attribute__((ext_vector_type(8)));
typedef float f32x4 __attribute__((ext_vector_type(4)));

__global__ __launch_bounds__(256) void agg_kernel(
    const float* __restrict__ nb_g,   // [POS][16][128]
    const float* __restrict__ wt_g,   // [POS][16]
    const float* __restrict__ ex_g,   // [POS][128]
    const float* __restrict__ w1_g,   // [129][128]
    const float* __restrict__ w2_g,   // [128]
    float* __restrict__ out_g,        // [POS][128]
    int pos_total)
{
    // B fragments of w1[:128] pre-packed in per-lane order: index
    // (e0*4+ik)*64+lane holds 8 bf16 = w1[ik*32+q*8+j][e0*16+m], q=lane>>4,
    // m=lane&15. Lane-contiguous 16B reads -> conflict-free ds_read_b128.
    __shared__ bf16x8 bfrag_lds[8 * 4 * 64];   // 32 KB
    __shared__ float  bias_lds[DIM];           // w1[128][:]
    __shared__ float  w2_lds[DIM];

    const int t = threadIdx.x;

    // One-time per block: pack w1 -> LDS fragments (strided reads, L2-cached)
    #pragma unroll
    for (int f0 = 0; f0 < 8; ++f0) {
        int f = f0 * 256 + t;
        int e0   = f >> 8;        // f / 256
        int ik   = (f >> 6) & 3;
        int lane = f & 63;
        int q = lane >> 4, m = lane & 15;
        bf16x8 v;
        #pragma unroll
        for (int j = 0; j < 8; ++j) {
            int d = ik * 32 + q * 8 + j;
            v[j] = (bf16_t)w1_g[d * DIM + e0 * 16 + m];
        }
        bfrag_lds[f] = v;
    }
    if (t < DIM) {
        bias_lds[t] = w1_g[128 * DIM + t];
        w2_lds[t]   = w2_g[t];
    }
    __syncthreads();

    const int wave = t >> 6;
    const int lane = t & 63;
    const int q = lane >> 4;    // 0..3
    const int m = lane & 15;    // 0..15
    const long wave_global = (long)blockIdx.x * WAVES_PER_BLOCK + wave;

    for (int it = 0; it < POS_PER_WAVE; ++it) {
        const long p = wave_global * POS_PER_WAVE + it;
        if (p >= pos_total) break;
        const float* nb = nb_g + p * (KN * DIM);
        const float* ex = ex_g + p * DIM;
        const float* wt = wt_g + p * KN;

        // neighbor_weight for this lane's 4 output rows (k = q*4+r)
        float wtq[4];
        #pragma unroll
        for (int r = 0; r < 4; ++r) wtq[r] = wt[q * 4 + r];

        // Load extra + neighbor pieces needed for A fragments (fp32, float4)
        // A[m][k_global = ik*32 + q*8 + j] = ex[c] * nb[m][c]
        f32x4 ex4[8], nb4[8];
        #pragma unroll
        for (int ik = 0; ik < 4; ++ik) {
            int c = ik * 32 + q * 8;
            ex4[ik * 2]     = *(const f32x4*)(ex + c);
            ex4[ik * 2 + 1] = *(const f32x4*)(ex + c + 4);
            nb4[ik * 2]     = *(const f32x4*)(nb + m * DIM + c);
            nb4[ik * 2 + 1] = *(const f32x4*)(nb + m * DIM + c + 4);
        }

        f32x4 acc[8];
        #pragma unroll
        for (int e0 = 0; e0 < 8; ++e0) acc[e0] = (f32x4){0.f, 0.f, 0.f, 0.f};

        #pragma unroll
        for (int ik = 0; ik < 4; ++ik) {
            bf16x8 afrag;
            #pragma unroll
            for (int j = 0; j < 4; ++j) {
                afrag[j]     = (bf16_t)(ex4[ik * 2][j]     * nb4[ik * 2][j]);
                afrag[j + 4] = (bf16_t)(ex4[ik * 2 + 1][j] * nb4[ik * 2 + 1][j]);
            }
            #pragma unroll
            for (int e0 = 0; e0 < 8; ++e0) {
                acc[e0] = __builtin_amdgcn_mfma_f32_16x16x32_bf16(
                    afrag, bfrag_lds[(e0 * 4 + ik) * 64 + lane], acc[e0], 0, 0, 0);
            }
        }

        // Epilogue. D layout: lane(q,m) holds alpha[row=q*4+r][col=e0*16+m]
        // z[r] = sum_e leaky_relu(alpha + wt*bias) * w2[e]   (fp32)
        float z[4] = {0.f, 0.f, 0.f, 0.f};
        #pragma unroll
        for (int e0 = 0; e0 < 8; ++e0) {
            float bias = bias_lds[e0 * 16 + m];
            float w2v  = w2_lds[e0 * 16 + m];
            #pragma unroll
            for (int r = 0; r < 4; ++r) {
                float a = acc[e0][r] + wtq[r] * bias;
                a = fmaxf(a, 0.2f * a);          // leaky_relu(0.2)
                z[r] += a * w2v;
            }
        }
        // reduce over the 16 m-lanes (columns e)
        #pragma unroll
        for (int s = 1; s <= 8; s <<= 1) {
            #pragma unroll
            for (int r = 0; r < 4; ++r) z[r] += __shfl_xor(z[r], s, 64);
        }

        // softmax over 16 rows; this lane holds rows q*4+r
        float mx = fmaxf(fmaxf(z[0], z[1]), fmaxf(z[2], z[3]));
        mx = fmaxf(mx, __shfl_xor(mx, 16, 64));
        mx = fmaxf(mx, __shfl_xor(mx, 32, 64));
        float e[4], part = 0.f;
        #pragma unroll
        for (int r = 0; r < 4; ++r) { e[r] = __expf(z[r] - mx); part += e[r]; }
        float denom = part;
        denom += __shfl_xor(denom, 16, 64);
        denom += __shfl_xor(denom, 32, 64);
        float inv = 1.f / denom;
        float al[4];
        #pragma unroll
        for (int r = 0; r < 4; ++r) al[r] = e[r] * inv;

        // broadcast alpha_k (k=0..15) to all lanes: row k lives in lanes with
        // q = k>>2 as al[k&3]
        float alpha[16];
        #pragma unroll
        for (int k = 0; k < 16; ++k)
            alpha[k] = __shfl(al[k & 3], (k >> 2) << 4, 64);

        // out[d] = sum_k alpha_k * nb[k][d]; lane owns d = 2*lane, 2*lane+1
        // (re-reads nb from global: L2-resident, no extra HBM)
        const int d0 = lane * 2;
        float ox = 0.f, oy = 0.f;
        #pragma unroll
        for (int k = 0; k < 16; ++k) {
            float2 v = *(const float2*)(nb + k * DIM + d0);
            ox += alpha[k] * v.x;
            oy += alpha[k] * v.y;
        }
        float2 o = {ox, oy};
        *(float2*)(out_g + p * DIM + d0) = o;
    }
}

extern "C" void kernel_launch(void* const* d_in, const int* in_sizes, int n_in,
                              void* d_out, int out_size, void* d_ws, size_t ws_size,
                              hipStream_t stream) {
    // inputs (setup_inputs order):
    // 0 self_vectors (unused), 1 neighbor_vector, 2 batch_size (unused),
    // 3 masks (unused), 4 neighbor_weight, 5 extra_vector, 6 w_1, 7 w_2
    const float* nb = (const float*)d_in[1];
    const float* wt = (const float*)d_in[4];
    const float* ex = (const float*)d_in[5];
    const float* w1 = (const float*)d_in[6];
    const float* w2 = (const float*)d_in[7];
    float* out = (float*)d_out;

    const int pos_total = in_sizes[5] / DIM;                 // B*N = 65536
    const int waves = (pos_total + POS_PER_WAVE - 1) / POS_PER_WAVE;
    const int blocks = (waves + WAVES_PER_BLOCK - 1) / WAVES_PER_BLOCK;  // 2048

    agg_kernel<<<blocks, 256, 0, stream>>>(nb, wt, ex, w1, w2, out, pos_total);
}